// Round 7
// baseline (141.746 us; speedup 1.0000x reference)
//
#include <hip/hip_runtime.h>

#define B_ 16
#define C_ 256
#define L_ 2048

using short8 = __attribute__((ext_vector_type(8))) short;
using f32x4  = __attribute__((ext_vector_type(4))) float;
using f32x16 = __attribute__((ext_vector_type(16))) float;
typedef unsigned int uint;

__device__ __forceinline__ unsigned short f2bf(float f) {
  unsigned u = __float_as_uint(f);
  return (unsigned short)((u + 0x7FFFu + ((u >> 16) & 1u)) >> 16);
}

__device__ __forceinline__ void gload16(const void* src, void* dst) {
  __builtin_amdgcn_global_load_lds(
      (const __attribute__((address_space(1))) unsigned int*)src,
      (__attribute__((address_space(3))) unsigned int*)dst, 16, 0, 0);
}

// ---------------- kernel 0: convert weights fp32 -> bf16 ----------------
__global__ __launch_bounds__(256) void convert_w(const float* __restrict__ wt,
                                                 const float* __restrict__ wp,
                                                 const float* __restrict__ wg,
                                                 unsigned short* __restrict__ dst) {
  int i = blockIdx.x * 256 + threadIdx.x;
  dst[i]          = f2bf(wt[i]);
  dst[65536 + i]  = f2bf(wp[i]);
  dst[131072 + i] = f2bf(wg[i]);
}

// ---------------- kernel 1: fused QKV projection (single pass over x) ----------------
// x staged to LDS once (32 KB, bf16, transposed+swizzled); p-loop stages W slices.
// p=0: qT[b,l,o] = (W_theta x + b)*log2e/16; p=1: kT; p=2: v[b,o,l].
__global__ __launch_bounds__(256, 2) void proj_kernel(
    const float* __restrict__ x, const unsigned short* __restrict__ wbf,
    const float* __restrict__ bth, const float* __restrict__ bph,
    const float* __restrict__ bg,
    unsigned short* __restrict__ qT, unsigned short* __restrict__ kT,
    unsigned short* __restrict__ vv)
{
  const int tid  = threadIdx.x;
  const int w    = tid >> 6;
  const int lane = tid & 63;
  const int r    = lane & 15;
  const int g    = lane >> 4;
  const int l0   = blockIdx.x * 64;
  const int b    = blockIdx.y;

  __shared__ unsigned short xs[64 * 256];   // x^T tile [l][c], swizzled (32 KB)
  __shared__ unsigned short wsd[256 * 64];  // W slice [o][c64], swizzled (32 KB)

  // ---- stage x^T once: fp32 -> bf16, transposed, 16B-granule row-XOR swizzle ----
#pragma unroll
  for (int it = 0; it < 64; ++it) {
    int l = (tid & 15) + 16 * (it & 3);
    int c = (tid >> 4) + 16 * (it >> 2);
    float xvv = x[((size_t)b * C_ + c) * L_ + l0 + l];
    xs[l * 256 + (((c >> 3) ^ (l & 7)) << 3) + (c & 7)] = f2bf(xvv);
  }

  f32x4 acc[4][4];
  for (int p = 0; p < 3; ++p) {
    const unsigned short* wsrc = wbf + p * 65536;
#pragma unroll
    for (int mi = 0; mi < 4; ++mi)
#pragma unroll
      for (int ni = 0; ni < 4; ++ni) acc[mi][ni] = f32x4{0.f, 0.f, 0.f, 0.f};

    for (int ks = 0; ks < 4; ++ks) {
      __syncthreads();   // prev mfma reads done (also covers xs writes on first iter)
#pragma unroll
      for (int it = 0; it < 8; ++it) {
        int o  = it * 32 + (tid >> 3);
        int cs = tid & 7;
        gload16(wsrc + o * C_ + ks * 64 + ((cs ^ (o & 7)) << 3),
                (void*)(wsd + (size_t)(it * 256 + w * 64) * 8));
      }
      __syncthreads();

#pragma unroll
      for (int kk2 = 0; kk2 < 2; ++kk2) {
        short8 xf[4], wf[4];
#pragma unroll
        for (int i = 0; i < 4; ++i) {
          int lrow = 16 * i + r;
          xf[i] = *(const short8*)(xs + lrow * 256 +
                                   (((8 * ks + 4 * kk2 + g) ^ (lrow & 7)) << 3));
          int orow = 64 * w + 16 * i + r;
          wf[i] = *(const short8*)(wsd + orow * 64 + (((kk2 * 4 + g) ^ (orow & 7)) << 3));
        }
        if (p < 2) {
#pragma unroll
          for (int mi = 0; mi < 4; ++mi)
#pragma unroll
            for (int ni = 0; ni < 4; ++ni)
              acc[mi][ni] = __builtin_amdgcn_mfma_f32_16x16x32_bf16(xf[mi], wf[ni], acc[mi][ni], 0, 0, 0);
        } else {
#pragma unroll
          for (int mi = 0; mi < 4; ++mi)
#pragma unroll
            for (int ni = 0; ni < 4; ++ni)
              acc[mi][ni] = __builtin_amdgcn_mfma_f32_16x16x32_bf16(wf[mi], xf[ni], acc[mi][ni], 0, 0, 0);
        }
      }
    }

    if (p < 2) {
      unsigned short* dst = (p == 0) ? qT : kT;
      const float* bias   = (p == 0) ? bth : bph;
      const float scale   = (p == 0) ? 0.09016844005556021f : 1.0f;  // log2e/16
#pragma unroll
      for (int ni = 0; ni < 4; ++ni) {
        int o    = 64 * w + 16 * ni + r;
        float bv = bias[o];
#pragma unroll
        for (int mi = 0; mi < 4; ++mi)
#pragma unroll
          for (int rr = 0; rr < 4; ++rr) {
            int l = l0 + 16 * mi + 4 * g + rr;
            dst[((size_t)b * L_ + l) * C_ + o] = f2bf((acc[mi][ni][rr] + bv) * scale);
          }
      }
    } else {
#pragma unroll
      for (int mi = 0; mi < 4; ++mi)
#pragma unroll
        for (int rr = 0; rr < 4; ++rr) {
          int o    = 64 * w + 16 * mi + 4 * g + rr;
          float bv = bg[o];
#pragma unroll
          for (int ni = 0; ni < 4; ++ni) {
            int l = l0 + 16 * ni + r;
            vv[((size_t)b * C_ + o) * L_ + l] = f2bf(acc[mi][ni][rr] + bv);
          }
        }
    }
  }
}

// ---------------- kernel 2: flash attention (round-6 structure, VALU diet) ----------------
// All inner-loop addresses precomputed (jt-invariant); tile loop unrolled x2 so the
// kls buffer toggle is a compile-time offset. exp/cvt via single-instruction asm.
__global__ __launch_bounds__(256, 2) void attn_kernel(
    const unsigned short* __restrict__ qT, const unsigned short* __restrict__ kT,
    const unsigned short* __restrict__ vv,
    const float* __restrict__ x, float* __restrict__ out)
{
  const int tid  = threadIdx.x;
  const int w    = tid >> 6;
  const int lane = tid & 63;
  const int l31  = lane & 31;
  const int hi   = lane >> 5;
  const int ih   = w >> 1;
  const int jh   = w & 1;

  int wg = ((blockIdx.x & 7) << 6) | (blockIdx.x >> 3);
  const int i0 = (wg & 31) * 64;
  const int b  = wg >> 5;

  __shared__ unsigned short kls[2][64 * 256];
  __shared__ unsigned short pls[64 * 64];
  __shared__ float lsums2[2][64];
  unsigned short* klsf = &kls[0][0];
  unsigned short* plsf = pls;

  const unsigned short* kTb = kT + (size_t)b * L_ * C_;
  const unsigned short* vvb = vv + (size_t)b * C_ * L_;

  // ---- hoisted Q fragments ----
  short8 qf[16];
  const unsigned short* qrow_p = qT + ((size_t)b * L_ + i0 + 32 * ih + l31) * C_;
#pragma unroll
  for (int ks = 0; ks < 16; ++ks)
    qf[ks] = *(const short8*)(qrow_p + ks * 16 + 8 * hi);

  // ---- precomputed addresses (all jt-invariant, element units) ----
  const int jrow = l31 + 32 * jh;
  int kfa[16];
#pragma unroll
  for (int k2 = 0; k2 < 8; ++k2) {
    kfa[2 * k2]     = jrow * 256 + (((4 * k2 + hi) ^ (jrow & 7)) << 3);
    kfa[2 * k2 + 1] = jrow * 256 + (((4 * k2 + 2 + hi) ^ (jrow & 7)) << 3);
  }
  int pfa[8];
#pragma unroll
  for (int ks = 0; ks < 4; ++ks)
#pragma unroll
    for (int it = 0; it < 2; ++it)
      pfa[2 * ks + it] = (l31 + 32 * it) * 64 + (((2 * ks + hi) ^ (l31 & 7)) << 3);
  int pwa[4];
  {
    const int i = l31 + 32 * ih;
#pragma unroll
    for (int q = 0; q < 4; ++q)
      pwa[q] = i * 64 + (((4 * jh + q) ^ (i & 7)) << 3) + 4 * hi;
  }
  const int koff0 = (tid >> 5) * 256 + (((tid & 31) ^ ((tid >> 5) & 7)) << 3);
  int voff[2];
#pragma unroll
  for (int ct = 0; ct < 2; ++ct) voff[ct] = (l31 + 32 * ct + 64 * w) * L_ + 8 * hi;

  f32x16 oacc[2][2];
#pragma unroll
  for (int it = 0; it < 2; ++it)
#pragma unroll
    for (int ct = 0; ct < 2; ++ct)
#pragma unroll
      for (int e = 0; e < 16; ++e) oacc[it][ct][e] = 0.f;
  float lsum = 0.f;

  // prologue: stage K tile 0 into buffer 0
  {
    const unsigned short* ksrc = kTb + koff0;
#pragma unroll
    for (int it = 0; it < 8; ++it)
      gload16(ksrc + it * 2048, (void*)(klsf + (it * 256 + w * 64) * 8));
  }
  const unsigned short* kstage = kTb + 16384;  // tile 1
  const unsigned short* vbase  = vvb;

#define TILE_BODY(CUR, NXT, DOSTAGE)                                               \
  {                                                                                \
    __syncthreads();                                                               \
    short8 vfr[2][4];                                                              \
    _Pragma("unroll")                                                              \
    for (int ct = 0; ct < 2; ++ct) {                                               \
      _Pragma("unroll")                                                            \
      for (int ks = 0; ks < 4; ++ks)                                               \
        vfr[ct][ks] = *(const short8*)(vbase + voff[ct] + 16 * ks);                \
    }                                                                              \
    if (DOSTAGE) {                                                                 \
      const unsigned short* ksrc = kstage + koff0;                                 \
      _Pragma("unroll")                                                            \
      for (int it = 0; it < 8; ++it)                                               \
        gload16(ksrc + it * 2048, (void*)(klsf + (NXT) + (it * 256 + w * 64) * 8));\
    }                                                                              \
    f32x16 sacc0, sacc1;                                                           \
    _Pragma("unroll")                                                              \
    for (int e = 0; e < 16; ++e) { sacc0[e] = 0.f; sacc1[e] = 0.f; }               \
    __builtin_amdgcn_s_setprio(1);                                                 \
    _Pragma("unroll")                                                              \
    for (int k2 = 0; k2 < 8; ++k2) {                                               \
      short8 kf0 = *(const short8*)(klsf + (CUR) + kfa[2 * k2]);                   \
      short8 kf1 = *(const short8*)(klsf + (CUR) + kfa[2 * k2 + 1]);               \
      sacc0 = __builtin_amdgcn_mfma_f32_32x32x16_bf16(kf0, qf[2 * k2], sacc0, 0, 0, 0);      \
      sacc1 = __builtin_amdgcn_mfma_f32_32x32x16_bf16(kf1, qf[2 * k2 + 1], sacc1, 0, 0, 0);  \
    }                                                                              \
    __builtin_amdgcn_s_setprio(0);                                                 \
    _Pragma("unroll")                                                              \
    for (int q = 0; q < 4; ++q) {                                                  \
      float s0 = sacc0[4 * q + 0] + sacc1[4 * q + 0];                              \
      float s1 = sacc0[4 * q + 1] + sacc1[4 * q + 1];                              \
      float s2 = sacc0[4 * q + 2] + sacc1[4 * q + 2];                              \
      float s3 = sacc0[4 * q + 3] + sacc1[4 * q + 3];                              \
      float p0, p1, p2, p3;                                                        \
      asm("v_exp_f32 %0, %1" : "=v"(p0) : "v"(s0));                                \
      asm("v_exp_f32 %0, %1" : "=v"(p1) : "v"(s1));                                \
      asm("v_exp_f32 %0, %1" : "=v"(p2) : "v"(s2));                                \
      asm("v_exp_f32 %0, %1" : "=v"(p3) : "v"(s3));                                \
      lsum += (p0 + p1) + (p2 + p3);                                               \
      uint dlo, dhi;                                                               \
      asm("v_cvt_pk_bf16_f32 %0, %1, %2" : "=v"(dlo) : "v"(p0), "v"(p1));          \
      asm("v_cvt_pk_bf16_f32 %0, %1, %2" : "=v"(dhi) : "v"(p2), "v"(p3));          \
      uint2 d2; d2.x = dlo; d2.y = dhi;                                            \
      *(uint2*)(plsf + pwa[q]) = d2;                                               \
    }                                                                              \
    __syncthreads();                                                               \
    __builtin_amdgcn_s_setprio(1);                                                 \
    _Pragma("unroll")                                                              \
    for (int ks = 0; ks < 4; ++ks) {                                               \
      short8 pf0 = *(const short8*)(plsf + pfa[2 * ks]);                           \
      short8 pf1 = *(const short8*)(plsf + pfa[2 * ks + 1]);                       \
      _Pragma("unroll")                                                            \
      for (int ct = 0; ct < 2; ++ct) {                                             \
        oacc[0][ct] = __builtin_amdgcn_mfma_f32_32x32x16_bf16(pf0, vfr[ct][ks], oacc[0][ct], 0, 0, 0); \
        oacc[1][ct] = __builtin_amdgcn_mfma_f32_32x32x16_bf16(pf1, vfr[ct][ks], oacc[1][ct], 0, 0, 0); \
      }                                                                            \
    }                                                                              \
    __builtin_amdgcn_s_setprio(0);                                                 \
    vbase += 64;                                                                   \
    if (DOSTAGE) kstage += 16384;                                                  \
  }

  for (int jt2 = 0; jt2 < 16; ++jt2) {
    TILE_BODY(0, 16384, 1)              // even tile: compute buf0, stage buf1
    TILE_BODY(16384, 0, (jt2 < 15))     // odd tile:  compute buf1, stage buf0
  }
#undef TILE_BODY

  // ---- lsum reduce + epilogue ----
  lsum += __shfl_xor(lsum, 32);
  if (lane < 32) lsums2[jh][32 * ih + l31] = lsum;
  __syncthreads();

#pragma unroll
  for (int it = 0; it < 2; ++it)
#pragma unroll
    for (int q = 0; q < 4; ++q) {
      int ib = 32 * it + 8 * q + 4 * hi;
      f32x4 ls0 = *(const f32x4*)(&lsums2[0][ib]);
      f32x4 ls1 = *(const f32x4*)(&lsums2[1][ib]);
      f32x4 linv;
#pragma unroll
      for (int rr = 0; rr < 4; ++rr) linv[rr] = 1.0f / (ls0[rr] + ls1[rr]);
#pragma unroll
      for (int ct = 0; ct < 2; ++ct) {
        int c = l31 + 32 * ct + 64 * w;
        size_t base = ((size_t)b * C_ + c) * L_ + i0 + ib;
        f32x4 xv = *(const f32x4*)(x + base);
        f32x4 ov;
#pragma unroll
        for (int rr = 0; rr < 4; ++rr)
          ov[rr] = xv[rr] + oacc[it][ct][4 * q + rr] * linv[rr];
        *(f32x4*)(out + base) = ov;
      }
    }
}

extern "C" void kernel_launch(void* const* d_in, const int* in_sizes, int n_in,
                              void* d_out, int out_size, void* d_ws, size_t ws_size,
                              hipStream_t stream) {
  (void)in_sizes; (void)n_in; (void)out_size; (void)ws_size;
  const float* x   = (const float*)d_in[0];
  const float* wt  = (const float*)d_in[1];
  const float* bt  = (const float*)d_in[2];
  const float* wp  = (const float*)d_in[3];
  const float* bp  = (const float*)d_in[4];
  const float* wg  = (const float*)d_in[5];
  const float* bgg = (const float*)d_in[6];
  float* out = (float*)d_out;

  char* ws = (char*)d_ws;
  unsigned short* wbf = (unsigned short*)ws;                              // 384 KB
  unsigned short* qT  = (unsigned short*)(ws + 393216);                   // 16 MB
  unsigned short* kT  = (unsigned short*)(ws + 393216 + 16777216);        // 16 MB
  unsigned short* vv  = (unsigned short*)(ws + 393216 + 2 * 16777216);    // 16 MB

  convert_w<<<dim3(256), dim3(256), 0, stream>>>(wt, wp, wg, wbf);
  proj_kernel<<<dim3(32, 16), dim3(256), 0, stream>>>(x, wbf, bt, bp, bgg, qT, kT, vv);
  attn_kernel<<<dim3(512), dim3(256), 0, stream>>>(qT, kT, vv, x, out);
}